// Round 5
// baseline (275.592 us; speedup 1.0000x reference)
//
#include <hip/hip_runtime.h>
#include <math.h>

#define NN 8192
#define CF 192
#define KNN 9
#define NSPL 4

__device__ __forceinline__ int group_start(int g) {
    // smallest i with batch[i]==g :  ceil(8191*g/8), capped at 8192
    int s = (8191 * g + 7) >> 3;
    return s > 8192 ? 8192 : s;
}

__device__ __forceinline__ float disf(int d) {
    return d > 0 ? 1.0f / sqrtf((float)d) : 0.0f;
}

// ---------------------------------------------------------------- transpose
// x [8,192,32,32] -> xf [8192][192]  (node = b*1024 + h*32 + w)
__global__ __launch_bounds__(256) void transpose_kernel(
    const float* __restrict__ x, float* __restrict__ xf)
{
    __shared__ float tile[32][65];
    int b = blockIdx.x, ct = blockIdx.y, ht = blockIdx.z;
    int c0 = ct * 32, hw0 = ht * 64;
    int tid = threadIdx.x;
#pragma unroll
    for (int p = 0; p < 8; ++p) {
        int c  = p * 4 + (tid >> 6);
        int hw = tid & 63;
        tile[c][hw] = x[(size_t)b * 196608 + (size_t)(c0 + c) * 1024 + hw0 + hw];
    }
    __syncthreads();
#pragma unroll
    for (int p = 0; p < 8; ++p) {
        int hw = p * 8 + (tid >> 5);
        int cc = tid & 31;
        xf[(size_t)(b * 1024 + hw0 + hw) * CF + c0 + cc] = tile[cc][hw];
    }
}

// ---------------------------------------------------------------- row norms (+ deg zero)
__global__ __launch_bounds__(256) void sq_kernel(
    const float* __restrict__ xf, float* __restrict__ sq, int* __restrict__ deg)
{
    int gt = blockIdx.x * 256 + threadIdx.x;
    if (gt < NN) deg[gt] = 0;            // fold memset into this pass
    int wid = gt >> 6;                   // node (one wave per node)
    int lane = gt & 63;
    float s = 0.0f;
#pragma unroll
    for (int p = 0; p < 3; ++p) {
        float v = xf[(size_t)wid * CF + p * 64 + lane];
        s = fmaf(v, v, s);
    }
#pragma unroll
    for (int off = 32; off > 0; off >>= 1) s += __shfl_xor(s, off, 64);
    if (lane == 0) sq[wid] = s;
}

// ---------------------------------------------------------------- kNN partial
// grid: 9 groups x 32 query-blocks(32 q) x 4 candidate-splits(256 c) = 1152
// blocks. LDS 37 KB -> 4 blocks/CU. Micro-tile cols tx*4 / 128+tx*4 so every
// ds_read_b128 sweeps all 32 banks; global->LDS staging is register-prefetch
// pipelined (kb+1 loads issued before kb's FMA block).
__global__ __launch_bounds__(256, 4) void knn_kernel(
    const float* __restrict__ xf, const float* __restrict__ sq,
    float* __restrict__ pk_d, int* __restrict__ pk_i)
{
    int bid = blockIdx.x;
    int g = bid >> 7;
    int rem = bid & 127;
    int qb = rem >> 2;
    int split = rem & 3;
    int gs = group_start(g);
    int gsize = group_start(g + 1) - gs;
    int q0 = qb * 32;
    int nq = gsize - q0; if (nq > 32) nq = 32;
    if (nq <= 0) return;                 // block-uniform; q's covered elsewhere
    int c0 = split * 256;
    int ncc = gsize - c0; if (ncc > 256) ncc = 256;

    int tid = threadIdx.x;

    float td[KNN]; int ti[KNN];
#pragma unroll
    for (int j = 0; j < KNN; ++j) { td[j] = __builtin_inff(); ti[j] = -1; }

    if (ncc <= 0) {                      // block-uniform: empty split
        if (tid < nq) {
            int q = gs + q0 + tid;
            size_t base = ((size_t)q * NSPL + split) * KNN;
#pragma unroll
            for (int j = 0; j < KNN; ++j) { pk_d[base + j] = td[j]; pk_i[base + j] = ti[j]; }
        }
        return;
    }

    // staging region (18944 B), overlaid by phase-1 partial lists (18432 B)
    __shared__ __align__(16) char smem[18944];
    float (*As)[36]  = (float(*)[36])smem;                    // 16x36x4 = 2304
    float (*Bs)[260] = (float(*)[260])(smem + 2304);          // 16x260x4 = 16640
    float (*ld)[KNN][32] = (float(*)[KNN][32])smem;           // [ch][j][q] 9216
    int   (*li)[KNN][32] = (int(*)[KNN][32])(smem + 9216);    // 9216
    __shared__ float Ds[32][132];        // dot tile, one 128-col half at a time
    __shared__ float sqc_s[256];
    __shared__ float sqq_s[32];

    int ty = tid >> 5;                   // rows ty*4 .. +3
    int tx = tid & 31;                   // cols tx*4 (half0), 128+tx*4 (half1)

    if (tid < 32) {
        int qo = q0 + tid; if (qo > gsize - 1) qo = gsize - 1;
        sqq_s[tid] = sq[gs + qo];
    }
    {
        int co = c0 + tid;
        sqc_s[tid] = (tid < ncc) ? sq[gs + co] : __builtin_inff();
    }

    // per-thread staging addresses (fixed across kb)
    int rA = tid >> 2, cA = (tid & 3) * 4;
    const float* aptr = xf;              // valid only for tid<128
    if (tid < 128) {
        int qo = q0 + rA; if (qo > gsize - 1) qo = gsize - 1;
        aptr = xf + (size_t)(gs + qo) * CF + cA;
    }
    const float* bptr[4];
    int rB[4], cB[4];
#pragma unroll
    for (int p2 = 0; p2 < 4; ++p2) {
        int t = tid + 256 * p2;
        rB[p2] = t >> 2; cB[p2] = (t & 3) * 4;
        int co = c0 + rB[p2]; if (co > gsize - 1) co = gsize - 1;
        bptr[p2] = xf + (size_t)(gs + co) * CF + cB[p2];
    }

    // prefetch kb = 0
    float4 pa = make_float4(0.f, 0.f, 0.f, 0.f);
    float4 pb[4];
    if (tid < 128) pa = *(const float4*)(aptr);
#pragma unroll
    for (int p2 = 0; p2 < 4; ++p2) pb[p2] = *(const float4*)(bptr[p2]);

    float acc[4][8];
#pragma unroll
    for (int i = 0; i < 4; ++i)
#pragma unroll
        for (int j = 0; j < 8; ++j) acc[i][j] = 0.0f;

    for (int kb = 0; kb < 12; ++kb) {
        __syncthreads();
        if (tid < 128) {
            As[cA + 0][rA] = pa.x; As[cA + 1][rA] = pa.y;
            As[cA + 2][rA] = pa.z; As[cA + 3][rA] = pa.w;
        }
#pragma unroll
        for (int p2 = 0; p2 < 4; ++p2) {
            Bs[cB[p2] + 0][rB[p2]] = pb[p2].x; Bs[cB[p2] + 1][rB[p2]] = pb[p2].y;
            Bs[cB[p2] + 2][rB[p2]] = pb[p2].z; Bs[cB[p2] + 3][rB[p2]] = pb[p2].w;
        }
        __syncthreads();
        if (kb < 11) {                   // issue kb+1 loads; drain during FMAs
            int off = (kb + 1) * 16;
            if (tid < 128) pa = *(const float4*)(aptr + off);
#pragma unroll
            for (int p2 = 0; p2 < 4; ++p2) pb[p2] = *(const float4*)(bptr[p2] + off);
        }
#pragma unroll
        for (int k = 0; k < 16; ++k) {
            float4 b0 = *(const float4*)&Bs[k][tx * 4];
            float4 b1 = *(const float4*)&Bs[k][128 + tx * 4];
            float bb[8] = {b0.x, b0.y, b0.z, b0.w, b1.x, b1.y, b1.z, b1.w};
            float aa[4];
#pragma unroll
            for (int i = 0; i < 4; ++i) aa[i] = As[k][ty * 4 + i];
#pragma unroll
            for (int i = 0; i < 4; ++i)
#pragma unroll
                for (int j = 0; j < 8; ++j)
                    acc[i][j] = fmaf(aa[i], bb[j], acc[i][j]);
        }
    }

    // ---- selection over two 128-column halves (candidates in index order)
    for (int h = 0; h < 2; ++h) {
        int hb = h * 128;
        __syncthreads();                 // FMA reads / prev phase2 done
        // write this half's dot products: all 256 threads, bank-uniform
#pragma unroll
        for (int i = 0; i < 4; ++i)
            *(float4*)&Ds[ty * 4 + i][tx * 4] =
                make_float4(acc[i][h * 4 + 0], acc[i][h * 4 + 1],
                            acc[i][h * 4 + 2], acc[i][h * 4 + 3]);
        __syncthreads();
        // phase1: thread -> (query q, chunk ch of 16 candidates, index order)
        {
            int q = tid >> 3, ch = tid & 7;
            float sqq = sqq_s[q];
            float pd[KNN]; int pi[KNN];
#pragma unroll
            for (int j = 0; j < KNN; ++j) { pd[j] = __builtin_inff(); pi[j] = -1; }
            for (int j16 = 0; j16 < 16; ++j16) {
                int c = ch * 16 + j16;
                float d = (sqq - 2.0f * Ds[q][c]) + sqc_s[hb + c];  // inf pad
                if (d < pd[KNN - 1]) {
                    pd[KNN - 1] = d; pi[KNN - 1] = gs + c0 + hb + c;
#pragma unroll
                    for (int j = KNN - 1; j > 0; --j) {
                        if (pd[j] < pd[j - 1]) {
                            float tf = pd[j]; pd[j] = pd[j - 1]; pd[j - 1] = tf;
                            int tn = pi[j]; pi[j] = pi[j - 1]; pi[j - 1] = tn;
                        }
                    }
                }
            }
#pragma unroll
            for (int j = 0; j < KNN; ++j) { ld[ch][j][q] = pd[j]; li[ch][j][q] = pi[j]; }
        }
        __syncthreads();
        // phase2: 32 threads merge 8 sorted lists (index order; early break)
        if (tid < 32) {
            for (int ch = 0; ch < 8; ++ch) {
#pragma unroll
                for (int j0 = 0; j0 < KNN; ++j0) {
                    float d = ld[ch][j0][tid];
                    if (!(d < td[KNN - 1])) break;   // sorted: rest can't insert
                    int id = li[ch][j0][tid];
                    td[KNN - 1] = d; ti[KNN - 1] = id;
#pragma unroll
                    for (int j = KNN - 1; j > 0; --j) {
                        if (td[j] < td[j - 1]) {
                            float tf = td[j]; td[j] = td[j - 1]; td[j - 1] = tf;
                            int tn = ti[j]; ti[j] = ti[j - 1]; ti[j - 1] = tn;
                        }
                    }
                }
            }
        }
    }

    if (tid < nq) {
        int q = gs + q0 + tid;
        size_t base = ((size_t)q * NSPL + split) * KNN;
#pragma unroll
        for (int j = 0; j < KNN; ++j) { pk_d[base + j] = td[j]; pk_i[base + j] = ti[j]; }
    }
}

// ---------------------------------------------------------------- merge + deg
__global__ __launch_bounds__(256) void merge_kernel(
    const float* __restrict__ pk_d, const int* __restrict__ pk_i,
    int* __restrict__ edges, int* __restrict__ deg)
{
    int q = blockIdx.x * 256 + threadIdx.x;
    if (q >= NN) return;
    float td[KNN]; int ti[KNN];
#pragma unroll
    for (int j = 0; j < KNN; ++j) { td[j] = __builtin_inff(); ti[j] = -1; }
    for (int s = 0; s < NSPL; ++s) {       // split order = index order (stable)
        size_t base = ((size_t)q * NSPL + s) * KNN;
#pragma unroll
        for (int j0 = 0; j0 < KNN; ++j0) {
            float d = pk_d[base + j0]; int id = pk_i[base + j0];
            if (d < td[KNN - 1]) {
                td[KNN - 1] = d; ti[KNN - 1] = id;
#pragma unroll
                for (int j = KNN - 1; j > 0; --j) {
                    if (td[j] < td[j - 1]) {
                        float tf = td[j]; td[j] = td[j - 1]; td[j - 1] = tf;
                        int tn = ti[j]; ti[j] = ti[j - 1]; ti[j - 1] = tn;
                    }
                }
            }
        }
    }
#pragma unroll
    for (int j = 0; j < KNN; ++j) {
        int id = ti[j];                   // -1 <=> invalid (d == inf)
        edges[q * KNN + j] = id;
        if (id >= 0 && id != q) atomicAdd(&deg[id], 1);
    }
}

// ---------------------------------------------------------------- fused Tx1 + out GEMM
// One block per 16-row stripe (512 blocks). W0/W1 k-tiles staged together so
// both matmuls accumulate in one kb sweep; W prefetched into registers so
// global latency overlaps the FMA block. LDS 50.3 KB.
__global__ __launch_bounds__(256, 2) void out_kernel(
    const float* __restrict__ xf, const int* __restrict__ edges,
    const int* __restrict__ deg, const float* __restrict__ W0,
    const float* __restrict__ W1, const float* __restrict__ bias,
    float* __restrict__ out)
{
    __shared__ float Ax[2][16][CF];      // [0]=xf rows, [1]=Tx1 rows (24.6 KB)
    __shared__ float Ws[2][16][CF];      // W0/W1 k-tiles (24.6 KB)
    __shared__ float coef_s[16][KNN];
    __shared__ int   nb_s[16][KNN];

    int r0 = blockIdx.x * 16;
    int tid = threadIdx.x;

    // W prefetch setup: 1536 float4 per kb tile, 6 per thread
    const float* wsrc[6];
    int ww[6], wr[6], wc[6];
    float4 pw[6];
#pragma unroll
    for (int p = 0; p < 6; ++p) {
        int f = p * 256 + tid;
        ww[p] = f / 768; wr[p] = (f % 768) / 48; wc[p] = (f % 48) * 4;
        wsrc[p] = (ww[p] ? W1 : W0) + (size_t)wr[p] * CF + wc[p];
        pw[p] = *(const float4*)(wsrc[p]);          // kb = 0
    }

    // stage xf rows: 16 rows x 48 float4 = 768
    for (int t = tid; t < 768; t += 256) {
        int i = t / 48, c4 = (t % 48) * 4;
        *(float4*)&Ax[0][i][c4] = *(const float4*)&xf[(size_t)(r0 + i) * CF + c4];
    }
    // coefficients: one (row, edge) per thread
    if (tid < 16 * KNN) {
        int i = tid / KNN, j = tid % KNN;
        int q = r0 + i;
        int id = edges[q * KNN + j];
        float cf = 0.0f; int s = q;
        if (id >= 0 && id != q) { cf = -disf(deg[id]) * disf(deg[q]); s = id; }
        coef_s[i][j] = cf; nb_s[i][j] = s;
    }
    __syncthreads();
    // gather Tx1 rows: 16*192 = 3072 elements
    for (int e = tid; e < 16 * CF; e += 256) {
        int i = e / CF, c = e % CF;
        float a = 0.0f;
#pragma unroll
        for (int t = 0; t < KNN; ++t)
            a = fmaf(coef_s[i][t], xf[(size_t)nb_s[i][t] * CF + c], a);
        Ax[1][i][c] = a;
    }

    int ty = tid >> 5, tx = tid & 31;    // rows {ty*2,ty*2+1}, cols {tx*2+64m}
    float acc[2][6];
#pragma unroll
    for (int i = 0; i < 2; ++i)
#pragma unroll
        for (int j = 0; j < 6; ++j) acc[i][j] = 0.0f;

    for (int kb = 0; kb < 12; ++kb) {
        __syncthreads();                 // kb=0: Ax[1] ready; else Ws consumed
#pragma unroll
        for (int p = 0; p < 6; ++p)
            *(float4*)&Ws[ww[p]][wr[p]][wc[p]] = pw[p];
        __syncthreads();
        if (kb < 11) {
            size_t off = (size_t)(kb + 1) * 16 * CF;
#pragma unroll
            for (int p = 0; p < 6; ++p) pw[p] = *(const float4*)(wsrc[p] + off);
        }
#pragma unroll
        for (int k = 0; k < 16; ++k) {
            float a0 = Ax[0][ty * 2 + 0][kb * 16 + k];
            float a1 = Ax[0][ty * 2 + 1][kb * 16 + k];
            float g0 = Ax[1][ty * 2 + 0][kb * 16 + k];
            float g1 = Ax[1][ty * 2 + 1][kb * 16 + k];
#pragma unroll
            for (int m = 0; m < 3; ++m) {
                float2 w0 = *(const float2*)&Ws[0][k][tx * 2 + 64 * m];
                float2 w1 = *(const float2*)&Ws[1][k][tx * 2 + 64 * m];
                acc[0][2 * m + 0] = fmaf(a0, w0.x, acc[0][2 * m + 0]);
                acc[0][2 * m + 1] = fmaf(a0, w0.y, acc[0][2 * m + 1]);
                acc[0][2 * m + 0] = fmaf(g0, w1.x, acc[0][2 * m + 0]);
                acc[0][2 * m + 1] = fmaf(g0, w1.y, acc[0][2 * m + 1]);
                acc[1][2 * m + 0] = fmaf(a1, w0.x, acc[1][2 * m + 0]);
                acc[1][2 * m + 1] = fmaf(a1, w0.y, acc[1][2 * m + 1]);
                acc[1][2 * m + 0] = fmaf(g1, w1.x, acc[1][2 * m + 0]);
                acc[1][2 * m + 1] = fmaf(g1, w1.y, acc[1][2 * m + 1]);
            }
        }
    }

#pragma unroll
    for (int i = 0; i < 2; ++i) {
        size_t ro = (size_t)(r0 + ty * 2 + i) * CF;
#pragma unroll
        for (int m = 0; m < 3; ++m) {
            float2 bv = *(const float2*)&bias[tx * 2 + 64 * m];
            float2 o;
            o.x = acc[i][2 * m + 0] + bv.x;
            o.y = acc[i][2 * m + 1] + bv.y;
            *(float2*)&out[ro + tx * 2 + 64 * m] = o;
        }
    }
}

// ---------------------------------------------------------------- launch
extern "C" void kernel_launch(void* const* d_in, const int* in_sizes, int n_in,
                              void* d_out, int out_size, void* d_ws, size_t ws_size,
                              hipStream_t stream)
{
    const float* x    = (const float*)d_in[0];
    const float* W0   = (const float*)d_in[1];
    const float* W1   = (const float*)d_in[2];
    const float* bias = (const float*)d_in[3];
    float* out = (float*)d_out;

    // Workspace: 6.65 MB (known-safe).
    char* ws = (char*)d_ws;
    float* xf    = (float*)ws;  ws += (size_t)NN * CF * 4;   // 6,291,456
    float* sq    = (float*)ws;  ws += (size_t)NN * 4;        //    32,768
    int*   edges = (int*)ws;    ws += (size_t)NN * KNN * 4;  //   294,912
    int*   deg   = (int*)ws;    ws += (size_t)NN * 4;        //    32,768

    // Partial top-k lists live in d_out (2.36 MB of its 6.29 MB); d_out is
    // fully overwritten by out_kernel afterwards, every call.
    float* pk_d = out;                                       // NN*NSPL*KNN
    int*   pk_i = (int*)(out + (size_t)NN * NSPL * KNN);     // NN*NSPL*KNN

    hipLaunchKernelGGL(transpose_kernel, dim3(8, 6, 16), dim3(256), 0, stream, x, xf);
    hipLaunchKernelGGL(sq_kernel, dim3(2048), dim3(256), 0, stream, xf, sq, deg);
    hipLaunchKernelGGL(knn_kernel, dim3(1152), dim3(256), 0, stream, xf, sq, pk_d, pk_i);
    hipLaunchKernelGGL(merge_kernel, dim3(32), dim3(256), 0, stream, pk_d, pk_i, edges, deg);
    hipLaunchKernelGGL(out_kernel, dim3(512), dim3(256), 0, stream,
                       xf, edges, deg, W0, W1, bias, out);
}

// Round 6
// 214.207 us; speedup vs baseline: 1.2866x; 1.2866x over previous
//
#include <hip/hip_runtime.h>
#include <math.h>

#define NN 8192
#define CF 192
#define KNN 9
#define NSPL 4

__device__ __forceinline__ int group_start(int g) {
    // smallest i with batch[i]==g :  ceil(8191*g/8), capped at 8192
    int s = (8191 * g + 7) >> 3;
    return s > 8192 ? 8192 : s;
}

__device__ __forceinline__ float disf(int d) {
    return d > 0 ? 1.0f / sqrtf((float)d) : 0.0f;
}

// ---------------------------------------------------------------- transpose
// x [8,192,32,32] -> xf [8192][192]  (node = b*1024 + h*32 + w)
__global__ __launch_bounds__(256) void transpose_kernel(
    const float* __restrict__ x, float* __restrict__ xf)
{
    __shared__ float tile[32][65];
    int b = blockIdx.x, ct = blockIdx.y, ht = blockIdx.z;
    int c0 = ct * 32, hw0 = ht * 64;
    int tid = threadIdx.x;
#pragma unroll
    for (int p = 0; p < 8; ++p) {
        int c  = p * 4 + (tid >> 6);
        int hw = tid & 63;
        tile[c][hw] = x[(size_t)b * 196608 + (size_t)(c0 + c) * 1024 + hw0 + hw];
    }
    __syncthreads();
#pragma unroll
    for (int p = 0; p < 8; ++p) {
        int hw = p * 8 + (tid >> 5);
        int cc = tid & 31;
        xf[(size_t)(b * 1024 + hw0 + hw) * CF + c0 + cc] = tile[cc][hw];
    }
}

// ---------------------------------------------------------------- row norms (+ deg zero)
__global__ __launch_bounds__(256) void sq_kernel(
    const float* __restrict__ xf, float* __restrict__ sq, int* __restrict__ deg)
{
    int gt = blockIdx.x * 256 + threadIdx.x;
    if (gt < NN) deg[gt] = 0;            // fold memset into this pass
    int wid = gt >> 6;                   // node (one wave per node)
    int lane = gt & 63;
    float s = 0.0f;
#pragma unroll
    for (int p = 0; p < 3; ++p) {
        float v = xf[(size_t)wid * CF + p * 64 + lane];
        s = fmaf(v, v, s);
    }
#pragma unroll
    for (int off = 32; off > 0; off >>= 1) s += __shfl_xor(s, off, 64);
    if (lane == 0) sq[wid] = s;
}

// ---------------------------------------------------------------- kNN partial
// grid: 9 groups x 32 query-blocks(32 q) x 4 candidate-splits(256 c) = 1152
// blocks. LDS ~36.4 KB -> 4 blocks/CU. Direct load->LDS staging (NO register
// prefetch: Round 5 showed it spills past the 64-VGPR budget -> 215 MB
// scratch traffic). Micro-tile cols tx*4 / 128+tx*4 (conflict-free b128).
// Selection: phase1 q=tid&31 (Ds stride 133 -> 32 lanes/32 banks), lists
// stride 33 (2-way max); phase2 early-break merge on 32 threads.
__global__ __launch_bounds__(256, 4) void knn_kernel(
    const float* __restrict__ xf, const float* __restrict__ sq,
    float* __restrict__ pk_d, int* __restrict__ pk_i)
{
    int bid = blockIdx.x;
    int g = bid >> 7;
    int rem = bid & 127;
    int qb = rem >> 2;
    int split = rem & 3;
    int gs = group_start(g);
    int gsize = group_start(g + 1) - gs;
    int q0 = qb * 32;
    int nq = gsize - q0; if (nq > 32) nq = 32;
    if (nq <= 0) return;                 // block-uniform; q's covered elsewhere
    int c0 = split * 256;
    int ncc = gsize - c0; if (ncc > 256) ncc = 256;

    int tid = threadIdx.x;

    float td[KNN]; int ti[KNN];
#pragma unroll
    for (int j = 0; j < KNN; ++j) { td[j] = __builtin_inff(); ti[j] = -1; }

    if (ncc <= 0) {                      // block-uniform: empty split
        if (tid < nq) {
            int q = gs + q0 + tid;
            size_t base = ((size_t)q * NSPL + split) * KNN;
#pragma unroll
            for (int j = 0; j < KNN; ++j) { pk_d[base + j] = td[j]; pk_i[base + j] = ti[j]; }
        }
        return;
    }

    // staging region (18944 B), overlaid by phase-1 partial lists (19008 B)
    __shared__ __align__(16) char smem[19072];
    float (*As)[36]  = (float(*)[36])smem;                    // 16x36x4  = 2304
    float (*Bs)[260] = (float(*)[260])(smem + 2304);          // 16x260x4 = 16640
    float (*ld)[KNN][33] = (float(*)[KNN][33])smem;           // 8x9x33x4 = 9504
    int   (*li)[KNN][33] = (int(*)[KNN][33])(smem + 9536);    // 9504
    __shared__ float Ds[32][133];        // dot tile, one 128-col half at a time
    __shared__ float sqc_s[256];
    __shared__ float sqq_s[32];

    int ty = tid >> 5;                   // rows ty*4 .. +3
    int tx = tid & 31;                   // cols tx*4 (half0), 128+tx*4 (half1)

    if (tid < 32) {
        int qo = q0 + tid; if (qo > gsize - 1) qo = gsize - 1;
        sqq_s[tid] = sq[gs + qo];
    }
    {
        int co = c0 + tid;
        sqc_s[tid] = (tid < ncc) ? sq[gs + co] : __builtin_inff();
    }

    float acc[4][8];
#pragma unroll
    for (int i = 0; i < 4; ++i)
#pragma unroll
        for (int j = 0; j < 8; ++j) acc[i][j] = 0.0f;

    for (int kb = 0; kb < 12; ++kb) {
        __syncthreads();
        if (tid < 128) {
            int r = tid >> 2, c4 = (tid & 3) * 4;
            int qo = q0 + r; if (qo > gsize - 1) qo = gsize - 1;
            float4 v = *(const float4*)(xf + (size_t)(gs + qo) * CF + kb * 16 + c4);
            As[c4 + 0][r] = v.x; As[c4 + 1][r] = v.y;
            As[c4 + 2][r] = v.z; As[c4 + 3][r] = v.w;
        }
#pragma unroll
        for (int p2 = 0; p2 < 4; ++p2) {
            int t = tid + 256 * p2;
            int r = t >> 2, c4 = (t & 3) * 4;
            int co = c0 + r; if (co > gsize - 1) co = gsize - 1;
            float4 v = *(const float4*)(xf + (size_t)(gs + co) * CF + kb * 16 + c4);
            Bs[c4 + 0][r] = v.x; Bs[c4 + 1][r] = v.y;
            Bs[c4 + 2][r] = v.z; Bs[c4 + 3][r] = v.w;
        }
        __syncthreads();
#pragma unroll
        for (int k = 0; k < 16; ++k) {
            float4 b0 = *(const float4*)&Bs[k][tx * 4];
            float4 b1 = *(const float4*)&Bs[k][128 + tx * 4];
            float bb[8] = {b0.x, b0.y, b0.z, b0.w, b1.x, b1.y, b1.z, b1.w};
            float aa[4];
#pragma unroll
            for (int i = 0; i < 4; ++i) aa[i] = As[k][ty * 4 + i];
#pragma unroll
            for (int i = 0; i < 4; ++i)
#pragma unroll
                for (int j = 0; j < 8; ++j)
                    acc[i][j] = fmaf(aa[i], bb[j], acc[i][j]);
        }
    }

    // ---- selection over two 128-column halves (candidates in index order)
    for (int h = 0; h < 2; ++h) {
        int hb = h * 128;
        __syncthreads();                 // FMA reads / prev phase2 done
        // write this half's dot products: all 256 threads, stride-133 rows
#pragma unroll
        for (int i = 0; i < 4; ++i)
            *(float4*)&Ds[ty * 4 + i][tx * 4] =
                make_float4(acc[i][h * 4 + 0], acc[i][h * 4 + 1],
                            acc[i][h * 4 + 2], acc[i][h * 4 + 3]);
        __syncthreads();
        // phase1: thread -> (query q = tid&31, chunk ch = tid>>5 of 16 cands)
        {
            int q = tid & 31, ch = tid >> 5;
            float sqq = sqq_s[q];
            float pd[KNN]; int pi[KNN];
#pragma unroll
            for (int j = 0; j < KNN; ++j) { pd[j] = __builtin_inff(); pi[j] = -1; }
            for (int j16 = 0; j16 < 16; ++j16) {
                int c = ch * 16 + j16;
                float d = (sqq - 2.0f * Ds[q][c]) + sqc_s[hb + c];  // inf pad
                if (d < pd[KNN - 1]) {
                    pd[KNN - 1] = d; pi[KNN - 1] = gs + c0 + hb + c;
#pragma unroll
                    for (int j = KNN - 1; j > 0; --j) {
                        if (pd[j] < pd[j - 1]) {
                            float tf = pd[j]; pd[j] = pd[j - 1]; pd[j - 1] = tf;
                            int tn = pi[j]; pi[j] = pi[j - 1]; pi[j - 1] = tn;
                        }
                    }
                }
            }
#pragma unroll
            for (int j = 0; j < KNN; ++j) { ld[ch][j][q] = pd[j]; li[ch][j][q] = pi[j]; }
        }
        __syncthreads();
        // phase2: 32 threads merge 8 sorted lists (index order; early break)
        if (tid < 32) {
            for (int ch = 0; ch < 8; ++ch) {
#pragma unroll
                for (int j0 = 0; j0 < KNN; ++j0) {
                    float d = ld[ch][j0][tid];
                    if (!(d < td[KNN - 1])) break;   // sorted: rest can't insert
                    int id = li[ch][j0][tid];
                    td[KNN - 1] = d; ti[KNN - 1] = id;
#pragma unroll
                    for (int j = KNN - 1; j > 0; --j) {
                        if (td[j] < td[j - 1]) {
                            float tf = td[j]; td[j] = td[j - 1]; td[j - 1] = tf;
                            int tn = ti[j]; ti[j] = ti[j - 1]; ti[j - 1] = tn;
                        }
                    }
                }
            }
        }
    }

    if (tid < nq) {
        int q = gs + q0 + tid;
        size_t base = ((size_t)q * NSPL + split) * KNN;
#pragma unroll
        for (int j = 0; j < KNN; ++j) { pk_d[base + j] = td[j]; pk_i[base + j] = ti[j]; }
    }
}

// ---------------------------------------------------------------- merge + deg
__global__ __launch_bounds__(256) void merge_kernel(
    const float* __restrict__ pk_d, const int* __restrict__ pk_i,
    int* __restrict__ edges, int* __restrict__ deg)
{
    int q = blockIdx.x * 256 + threadIdx.x;
    if (q >= NN) return;
    float td[KNN]; int ti[KNN];
#pragma unroll
    for (int j = 0; j < KNN; ++j) { td[j] = __builtin_inff(); ti[j] = -1; }
    for (int s = 0; s < NSPL; ++s) {       // split order = index order (stable)
        size_t base = ((size_t)q * NSPL + s) * KNN;
#pragma unroll
        for (int j0 = 0; j0 < KNN; ++j0) {
            float d = pk_d[base + j0]; int id = pk_i[base + j0];
            if (d < td[KNN - 1]) {
                td[KNN - 1] = d; ti[KNN - 1] = id;
#pragma unroll
                for (int j = KNN - 1; j > 0; --j) {
                    if (td[j] < td[j - 1]) {
                        float tf = td[j]; td[j] = td[j - 1]; td[j - 1] = tf;
                        int tn = ti[j]; ti[j] = ti[j - 1]; ti[j - 1] = tn;
                    }
                }
            }
        }
    }
#pragma unroll
    for (int j = 0; j < KNN; ++j) {
        int id = ti[j];                   // -1 <=> invalid (d == inf)
        edges[q * KNN + j] = id;
        if (id >= 0 && id != q) atomicAdd(&deg[id], 1);
    }
}

// ---------------------------------------------------------------- fused Tx1 + out GEMM
// One block per 16-row stripe (512 blocks). W0/W1 k-tiles staged together so
// both matmuls accumulate in one kb sweep; W prefetched into registers (OK
// here: (256,2) -> 256-VGPR budget, no spill). LDS 50.3 KB.
__global__ __launch_bounds__(256, 2) void out_kernel(
    const float* __restrict__ xf, const int* __restrict__ edges,
    const int* __restrict__ deg, const float* __restrict__ W0,
    const float* __restrict__ W1, const float* __restrict__ bias,
    float* __restrict__ out)
{
    __shared__ float Ax[2][16][CF];      // [0]=xf rows, [1]=Tx1 rows (24.6 KB)
    __shared__ float Ws[2][16][CF];      // W0/W1 k-tiles (24.6 KB)
    __shared__ float coef_s[16][KNN];
    __shared__ int   nb_s[16][KNN];

    int r0 = blockIdx.x * 16;
    int tid = threadIdx.x;

    // W prefetch setup: 1536 float4 per kb tile, 6 per thread
    const float* wsrc[6];
    int ww[6], wr[6], wc[6];
    float4 pw[6];
#pragma unroll
    for (int p = 0; p < 6; ++p) {
        int f = p * 256 + tid;
        ww[p] = f / 768; wr[p] = (f % 768) / 48; wc[p] = (f % 48) * 4;
        wsrc[p] = (ww[p] ? W1 : W0) + (size_t)wr[p] * CF + wc[p];
        pw[p] = *(const float4*)(wsrc[p]);          // kb = 0
    }

    // stage xf rows: 16 rows x 48 float4 = 768
    for (int t = tid; t < 768; t += 256) {
        int i = t / 48, c4 = (t % 48) * 4;
        *(float4*)&Ax[0][i][c4] = *(const float4*)&xf[(size_t)(r0 + i) * CF + c4];
    }
    // coefficients: one (row, edge) per thread
    if (tid < 16 * KNN) {
        int i = tid / KNN, j = tid % KNN;
        int q = r0 + i;
        int id = edges[q * KNN + j];
        float cf = 0.0f; int s = q;
        if (id >= 0 && id != q) { cf = -disf(deg[id]) * disf(deg[q]); s = id; }
        coef_s[i][j] = cf; nb_s[i][j] = s;
    }
    __syncthreads();
    // gather Tx1 rows: 16*192 = 3072 elements
    for (int e = tid; e < 16 * CF; e += 256) {
        int i = e / CF, c = e % CF;
        float a = 0.0f;
#pragma unroll
        for (int t = 0; t < KNN; ++t)
            a = fmaf(coef_s[i][t], xf[(size_t)nb_s[i][t] * CF + c], a);
        Ax[1][i][c] = a;
    }

    int ty = tid >> 5, tx = tid & 31;    // rows {ty*2,ty*2+1}, cols {tx*2+64m}
    float acc[2][6];
#pragma unroll
    for (int i = 0; i < 2; ++i)
#pragma unroll
        for (int j = 0; j < 6; ++j) acc[i][j] = 0.0f;

    for (int kb = 0; kb < 12; ++kb) {
        __syncthreads();                 // kb=0: Ax[1] ready; else Ws consumed
#pragma unroll
        for (int p = 0; p < 6; ++p)
            *(float4*)&Ws[ww[p]][wr[p]][wc[p]] = pw[p];
        __syncthreads();
        if (kb < 11) {
            size_t off = (size_t)(kb + 1) * 16 * CF;
#pragma unroll
            for (int p = 0; p < 6; ++p) pw[p] = *(const float4*)(wsrc[p] + off);
        }
#pragma unroll
        for (int k = 0; k < 16; ++k) {
            float a0 = Ax[0][ty * 2 + 0][kb * 16 + k];
            float a1 = Ax[0][ty * 2 + 1][kb * 16 + k];
            float g0 = Ax[1][ty * 2 + 0][kb * 16 + k];
            float g1 = Ax[1][ty * 2 + 1][kb * 16 + k];
#pragma unroll
            for (int m = 0; m < 3; ++m) {
                float2 w0 = *(const float2*)&Ws[0][k][tx * 2 + 64 * m];
                float2 w1 = *(const float2*)&Ws[1][k][tx * 2 + 64 * m];
                acc[0][2 * m + 0] = fmaf(a0, w0.x, acc[0][2 * m + 0]);
                acc[0][2 * m + 1] = fmaf(a0, w0.y, acc[0][2 * m + 1]);
                acc[0][2 * m + 0] = fmaf(g0, w1.x, acc[0][2 * m + 0]);
                acc[0][2 * m + 1] = fmaf(g0, w1.y, acc[0][2 * m + 1]);
                acc[1][2 * m + 0] = fmaf(a1, w0.x, acc[1][2 * m + 0]);
                acc[1][2 * m + 1] = fmaf(a1, w0.y, acc[1][2 * m + 1]);
                acc[1][2 * m + 0] = fmaf(g1, w1.x, acc[1][2 * m + 0]);
                acc[1][2 * m + 1] = fmaf(g1, w1.y, acc[1][2 * m + 1]);
            }
        }
    }

#pragma unroll
    for (int i = 0; i < 2; ++i) {
        size_t ro = (size_t)(r0 + ty * 2 + i) * CF;
#pragma unroll
        for (int m = 0; m < 3; ++m) {
            float2 bv = *(const float2*)&bias[tx * 2 + 64 * m];
            float2 o;
            o.x = acc[i][2 * m + 0] + bv.x;
            o.y = acc[i][2 * m + 1] + bv.y;
            *(float2*)&out[ro + tx * 2 + 64 * m] = o;
        }
    }
}

// ---------------------------------------------------------------- launch
extern "C" void kernel_launch(void* const* d_in, const int* in_sizes, int n_in,
                              void* d_out, int out_size, void* d_ws, size_t ws_size,
                              hipStream_t stream)
{
    const float* x    = (const float*)d_in[0];
    const float* W0   = (const float*)d_in[1];
    const float* W1   = (const float*)d_in[2];
    const float* bias = (const float*)d_in[3];
    float* out = (float*)d_out;

    // Workspace: 6.65 MB (known-safe).
    char* ws = (char*)d_ws;
    float* xf    = (float*)ws;  ws += (size_t)NN * CF * 4;   // 6,291,456
    float* sq    = (float*)ws;  ws += (size_t)NN * 4;        //    32,768
    int*   edges = (int*)ws;    ws += (size_t)NN * KNN * 4;  //   294,912
    int*   deg   = (int*)ws;    ws += (size_t)NN * 4;        //    32,768

    // Partial top-k lists live in d_out (2.36 MB of its 6.29 MB); d_out is
    // fully overwritten by out_kernel afterwards, every call.
    float* pk_d = out;                                       // NN*NSPL*KNN
    int*   pk_i = (int*)(out + (size_t)NN * NSPL * KNN);     // NN*NSPL*KNN

    hipLaunchKernelGGL(transpose_kernel, dim3(8, 6, 16), dim3(256), 0, stream, x, xf);
    hipLaunchKernelGGL(sq_kernel, dim3(2048), dim3(256), 0, stream, xf, sq, deg);
    hipLaunchKernelGGL(knn_kernel, dim3(1152), dim3(256), 0, stream, xf, sq, pk_d, pk_i);
    hipLaunchKernelGGL(merge_kernel, dim3(32), dim3(256), 0, stream, pk_d, pk_i, edges, deg);
    hipLaunchKernelGGL(out_kernel, dim3(512), dim3(256), 0, stream,
                       xf, edges, deg, W0, W1, bias, out);
}